// Round 3
// baseline (211.593 us; speedup 1.0000x reference)
//
#include <hip/hip_runtime.h>

// ============================================================================
// QuantumHeadAmplitude: 256 x 16-qubit statevector sim, 2 StronglyEntangling
// layers, Z-expvals, linear head.
//
// Algebra (validated R1/R2): CNOTs virtualized as GF(2) index maps.
// stored[x] = psi_true[A^{-1} x]; L1 Rot on wire w => generalized 1q gate,
// mask col_w(A), role row_w(A^{-1}); expvals via final A^{-1} rows; deferred
// normalization (ev = sv/tot).
//
// R3: passA/passB use 512 threads x 16 amps (4 reg bits) for 24 waves/CU
// (launch_bounds(512,6), 32KB LDS -> 3 blocks/CU), vectorized global access
// (float4 in, dwordx2/dwordx4 state), rank-5 XOR-hash LDS exchanges.
// passC / head / prep unchanged from R2 (validated).
// ============================================================================

#define BATCH 256
#define NCLS 10

typedef float v2f __attribute__((ext_vector_type(2)));
typedef _Float16 f16x2 __attribute__((ext_vector_type(2)));

struct CircuitMeta { unsigned l1mask[16]; unsigned l1role[16]; unsigned fin[16]; };

__host__ __device__ constexpr CircuitMeta make_meta() {
  CircuitMeta m{};
  unsigned col[16], inv[16];
  for (int w = 0; w < 16; ++w) { col[w] = 1u << (15 - w); inv[w] = 1u << (15 - w); }
  for (int w = 0; w < 16; ++w) { int c = w, t = (w + 1) & 15; col[c] ^= col[t]; inv[t] ^= inv[c]; }
  for (int w = 0; w < 16; ++w) { m.l1mask[w] = col[w]; m.l1role[w] = inv[w]; }
  for (int w = 0; w < 16; ++w) { int c = w, t = (w + 2) & 15; col[c] ^= col[t]; inv[t] ^= inv[c]; }
  for (int w = 0; w < 16; ++w) m.fin[w] = inv[w];
  return m;
}
constexpr CircuitMeta META = make_meta();

// Rank-5 XOR-hash for LDS bank spread (GF2-linear, invertible on 13 bits:
// only bits 0..3 are modified by functions of bits 4..12).
__host__ __device__ constexpr unsigned HSH(unsigned p) {
  return p ^ ((p >> 4) & 15u) ^ ((p >> 8) & 15u) ^ ((p >> 5) & 3u);
}
// packed(13b) -> global index bits for passB local set {15..10, 6..0}
__host__ __device__ constexpr unsigned GIDX(unsigned p) {
  return (p & 0x7Fu) | ((p & 0x1F80u) << 3);
}

__device__ __forceinline__ v2f swp(v2f a) { return __builtin_shufflevector(a, a, 1, 0); }
__device__ __forceinline__ unsigned PK(v2f a) {
  return __builtin_bit_cast(unsigned, __builtin_amdgcn_cvt_pkrtz(a.x, a.y));
}
__device__ __forceinline__ v2f UNPK(unsigned u) {
  f16x2 h = __builtin_bit_cast(f16x2, u);
  return (v2f){(float)h.x, (float)h.y};
}

template<int B0,int B1,int B2,int B3>
__host__ __device__ constexpr unsigned regval4(int j) {
  return ((unsigned)(j & 1) << B0) | ((unsigned)((j >> 1) & 1) << B1) |
         ((unsigned)((j >> 2) & 1) << B2) | ((unsigned)((j >> 3) & 1) << B3);
}
template<int B0,int B1,int B2,int B3,int B4>
__host__ __device__ constexpr unsigned regval5(int j) {
  return regval4<B0,B1,B2,B3>(j) | ((unsigned)((j >> 4) & 1) << B4);
}

// Generalized 1q gate over 16 register-resident amps (4 reg bits at global
// positions B0..B3). MG = XOR mask (static-checked within reg set), RG = role
// row. tp = thread's non-reg global bits. Role parity = parity(RG&tp)
// [hoisted U-vs-XUX select] ^ parity(RG&regval(j)) [compile-time renaming].
template<int B0,int B1,int B2,int B3, unsigned MG, unsigned RG>
__device__ __forceinline__ void gate4(v2f (&A)[16], const float* __restrict__ g,
                                      int gi, unsigned tp) {
  constexpr unsigned cover = (1u<<B0)|(1u<<B1)|(1u<<B2)|(1u<<B3);
  static_assert((MG & ~cover) == 0u, "gate mask not covered by stage reg bits");
  constexpr unsigned mr = ((MG>>B0)&1u) | (((MG>>B1)&1u)<<1) | (((MG>>B2)&1u)<<2)
                        | (((MG>>B3)&1u)<<3);
  static_assert(mr != 0u, "empty reg mask");
  constexpr unsigned pivot = mr & (0u - mr);

  float u00r = g[gi*8+0], u00i = g[gi*8+1], u01r = g[gi*8+2], u01i = g[gi*8+3];
  float u10r = g[gi*8+4], u10i = g[gi*8+5], u11r = g[gi*8+6], u11i = g[gi*8+7];
  const bool s = (__popc(RG & tp) & 1) != 0;
  float e00r = s ? u11r : u00r, e00i = s ? u11i : u00i;
  float e01r = s ? u10r : u01r, e01i = s ? u10i : u01i;
  float e10r = s ? u01r : u10r, e10i = s ? u01i : u10i;
  float e11r = s ? u00r : u11r, e11i = s ? u00i : u11i;
  v2f a00 = {e00r, e00r}, b00 = {-e00i, e00i};
  v2f a01 = {e01r, e01r}, b01 = {-e01i, e01i};
  v2f a10 = {e10r, e10r}, b10 = {-e10i, e10i};
  v2f a11 = {e11r, e11r}, b11 = {-e11i, e11i};

  #pragma unroll
  for (int j0 = 0; j0 < 16; ++j0) {
    if (j0 & (int)pivot) continue;
    const int j1 = j0 ^ (int)mr;
    const bool podd =
      (__builtin_popcount(RG & regval4<B0,B1,B2,B3>(j0)) & 1) != 0;  // folds
    v2f v0 = A[j0], v1 = A[j1];
    v2f v0s = swp(v0), v1s = swp(v1);
    if (!podd) {
      A[j0] = a00*v0 + b00*v0s + a01*v1 + b01*v1s;
      A[j1] = a10*v0 + b10*v0s + a11*v1 + b11*v1s;
    } else {
      A[j0] = a11*v0 + b11*v0s + a10*v1 + b10*v1s;
      A[j1] = a01*v0 + b01*v0s + a00*v1 + b00*v1s;
    }
  }
}

// 5-bit variant for passC (256 threads x 32 amps) — unchanged from R2.
template<int B0,int B1,int B2,int B3,int B4, unsigned MG, unsigned RG>
__device__ __forceinline__ void gate5(v2f (&A)[32], const float* __restrict__ g,
                                      int gi, unsigned tp) {
  constexpr unsigned cover = (1u<<B0)|(1u<<B1)|(1u<<B2)|(1u<<B3)|(1u<<B4);
  static_assert((MG & ~cover) == 0u, "gate mask not covered by stage reg bits");
  constexpr unsigned mr = ((MG>>B0)&1u) | (((MG>>B1)&1u)<<1) | (((MG>>B2)&1u)<<2)
                        | (((MG>>B3)&1u)<<3) | (((MG>>B4)&1u)<<4);
  static_assert(mr != 0u, "empty reg mask");
  constexpr unsigned pivot = mr & (0u - mr);

  float u00r = g[gi*8+0], u00i = g[gi*8+1], u01r = g[gi*8+2], u01i = g[gi*8+3];
  float u10r = g[gi*8+4], u10i = g[gi*8+5], u11r = g[gi*8+6], u11i = g[gi*8+7];
  const bool s = (__popc(RG & tp) & 1) != 0;
  float e00r = s ? u11r : u00r, e00i = s ? u11i : u00i;
  float e01r = s ? u10r : u01r, e01i = s ? u10i : u01i;
  float e10r = s ? u01r : u10r, e10i = s ? u01i : u10i;
  float e11r = s ? u00r : u11r, e11i = s ? u00i : u11i;
  v2f a00 = {e00r, e00r}, b00 = {-e00i, e00i};
  v2f a01 = {e01r, e01r}, b01 = {-e01i, e01i};
  v2f a10 = {e10r, e10r}, b10 = {-e10i, e10i};
  v2f a11 = {e11r, e11r}, b11 = {-e11i, e11i};

  #pragma unroll
  for (int j0 = 0; j0 < 32; ++j0) {
    if (j0 & (int)pivot) continue;
    const int j1 = j0 ^ (int)mr;
    const bool podd =
      (__builtin_popcount(RG & regval5<B0,B1,B2,B3,B4>(j0)) & 1) != 0;
    v2f v0 = A[j0], v1 = A[j1];
    v2f v0s = swp(v0), v1s = swp(v1);
    if (!podd) {
      A[j0] = a00*v0 + b00*v0s + a01*v1 + b01*v1s;
      A[j1] = a10*v0 + b10*v0s + a11*v1 + b11*v1s;
    } else {
      A[j0] = a11*v0 + b11*v0s + a10*v1 + b10*v1s;
      A[j1] = a01*v0 + b01*v0s + a00*v1 + b00*v1s;
    }
  }
}

// Rot(phi,theta,omega) = RZ(omega) RY(theta) RZ(phi) -> 32 gates x 8 floats
__global__ void prep_gates(const float* __restrict__ qp, float* __restrict__ g) {
  int i = threadIdx.x;
  if (i >= 32) return;
  float phi = qp[i*3+0], th = qp[i*3+1], om = qp[i*3+2];
  float cth = cosf(0.5f*th), sth = sinf(0.5f*th);
  float a = 0.5f*(phi+om), d = 0.5f*(phi-om);
  float ca = cosf(a), sa = sinf(a), cd = cosf(d), sd = sinf(d);
  g[i*8+0] =  ca*cth; g[i*8+1] = -sa*cth;
  g[i*8+2] = -cd*sth; g[i*8+3] = -sd*sth;
  g[i*8+4] =  cd*sth; g[i*8+5] = -sd*sth;
  g[i*8+6] =  ca*cth; g[i*8+7] =  sa*cth;
}

// ---------------------------------------------------------------------------
// PASS A: fixed g{15,14,13}=f (8 vals), local p == g{12..0}. 512 thr x 16 amp.
// L0 wires 3..15 (bits 12..0), tp=0 (roles always in reg bits).
// Stages: S1 reg g{0,1,11,12} (float4 load), S2 g{7,8,9,10}, S3 g{3,4,5,6},
//         S4 g{0,1,2,12} (dwordx4 store).
// ---------------------------------------------------------------------------
__global__ __launch_bounds__(512, 6) void passA(const float* __restrict__ x,
    unsigned* __restrict__ st, const float* __restrict__ g) {
  __shared__ unsigned L[8192];
  const int t = threadIdx.x;                 // 9 bits
  const int batch = blockIdx.x >> 3;
  const unsigned f = blockIdx.x & 7;
  const float4* xb4 = (const float4*)(x + ((size_t)batch << 16) + ((size_t)f << 13));

  // S1 layout: p = (t<<2) | (j&3) | ((j&12)<<9)  [j0->g0, j1->g1, j2->g11, j3->g12]
  v2f A[16];
  #pragma unroll
  for (int jh = 0; jh < 4; ++jh) {
    float4 v = xb4[(unsigned)t | ((unsigned)jh << 9)];
    A[jh*4+0] = (v2f){v.x, 0.f}; A[jh*4+1] = (v2f){v.y, 0.f};
    A[jh*4+2] = (v2f){v.z, 0.f}; A[jh*4+3] = (v2f){v.w, 0.f};
  }

  gate4<0,1,11,12, 0x0001u,0x0001u>(A, g, 15, 0u);  // wire15 (g0)
  gate4<0,1,11,12, 0x0002u,0x0002u>(A, g, 14, 0u);  // wire14 (g1)
  gate4<0,1,11,12, 0x0800u,0x0800u>(A, g,  4, 0u);  // wire4  (g11)
  gate4<0,1,11,12, 0x1000u,0x1000u>(A, g,  3, 0u);  // wire3  (g12)

  // E1 -> S2: tsp2 = (t&0x7F)|((t&0x180)<<4), jsp2 = j<<7
  {
    const unsigned wb = HSH((unsigned)t << 2);
    #pragma unroll
    for (int j = 0; j < 16; ++j)
      L[wb ^ HSH(((unsigned)j & 3u) | (((unsigned)j & 12u) << 9))] = PK(A[j]);
    __syncthreads();
    const unsigned rb = HSH(((unsigned)t & 0x7Fu) | (((unsigned)t & 0x180u) << 4));
    #pragma unroll
    for (int j = 0; j < 16; ++j) A[j] = UNPK(L[rb ^ HSH((unsigned)j << 7)]);
  }

  gate4<7,8,9,10, 0x0080u,0x0080u>(A, g, 8, 0u);   // wire8  (g7)
  gate4<7,8,9,10, 0x0100u,0x0100u>(A, g, 7, 0u);   // wire7  (g8)
  gate4<7,8,9,10, 0x0200u,0x0200u>(A, g, 6, 0u);   // wire6  (g9)
  gate4<7,8,9,10, 0x0400u,0x0400u>(A, g, 5, 0u);   // wire5  (g10)

  // E2 -> S3: tsp3 = (t&7)|((t&0x1F8)<<4), jsp3 = j<<3
  __syncthreads();
  {
    const unsigned wb = HSH(((unsigned)t & 0x7Fu) | (((unsigned)t & 0x180u) << 4));
    #pragma unroll
    for (int j = 0; j < 16; ++j) L[wb ^ HSH((unsigned)j << 7)] = PK(A[j]);
    __syncthreads();
    const unsigned rb = HSH(((unsigned)t & 7u) | (((unsigned)t & 0x1F8u) << 4));
    #pragma unroll
    for (int j = 0; j < 16; ++j) A[j] = UNPK(L[rb ^ HSH((unsigned)j << 3)]);
  }

  gate4<3,4,5,6, 0x0008u,0x0008u>(A, g, 12, 0u);   // wire12 (g3)
  gate4<3,4,5,6, 0x0010u,0x0010u>(A, g, 11, 0u);   // wire11 (g4)
  gate4<3,4,5,6, 0x0020u,0x0020u>(A, g, 10, 0u);   // wire10 (g5)
  gate4<3,4,5,6, 0x0040u,0x0040u>(A, g,  9, 0u);   // wire9  (g6)

  // E3 -> S4: tsp4 = t<<3, jsp4 = (j&7)|((j&8)<<9)
  __syncthreads();
  {
    const unsigned wb = HSH(((unsigned)t & 7u) | (((unsigned)t & 0x1F8u) << 4));
    #pragma unroll
    for (int j = 0; j < 16; ++j) L[wb ^ HSH((unsigned)j << 3)] = PK(A[j]);
    __syncthreads();
    const unsigned rb = HSH((unsigned)t << 3);
    #pragma unroll
    for (int j = 0; j < 16; ++j)
      A[j] = UNPK(L[rb ^ HSH(((unsigned)j & 7u) | (((unsigned)j & 8u) << 9))]);
  }

  gate4<0,1,2,12, 0x0004u,0x0004u>(A, g, 13, 0u);  // wire13 (g2)

  // Store: base = (f<<13)|(t<<3); j0..2 -> g0..2 (8 consecutive dwords),
  // j3 -> g12 (+4096)
  unsigned* outb = st + ((size_t)batch << 16) + ((size_t)f << 13) + ((size_t)t << 3);
  #pragma unroll
  for (int h = 0; h < 2; ++h) {
    uint4 q0, q1;
    q0.x = PK(A[h*8+0]); q0.y = PK(A[h*8+1]); q0.z = PK(A[h*8+2]); q0.w = PK(A[h*8+3]);
    q1.x = PK(A[h*8+4]); q1.y = PK(A[h*8+5]); q1.z = PK(A[h*8+6]); q1.w = PK(A[h*8+7]);
    *(uint4*)(outb + h*4096 + 0) = q0;
    *(uint4*)(outb + h*4096 + 4) = q1;
  }
}

// ---------------------------------------------------------------------------
// PASS B: fixed g{9,8,7}=c (8 vals), local = {15..10,6..0} (packed p: g6..0 ->
// p6..0, g15..10 -> p12..7). 512 thr x 16 amps.
// Stages: S1 g{0,13,14,15}: L0 w0,w1,w2 then L1 w0,w1,w15 (dwordx2 load)
//         S2 g{10,11,12,13}: L1 w2,w3,w4
//         S3 g{3,4,5,6}:     L1 w9,w10,w11
//         S4 g{0,1,2,3}:     L1 w12,w13,w14 (dwordx4 store)
// (All L1 gates pairwise commute — roles are nested prefixes.)
// ---------------------------------------------------------------------------
__global__ __launch_bounds__(512, 6) void passB(unsigned* __restrict__ st,
    const float* __restrict__ g) {
  __shared__ unsigned L[8192];
  const int t = threadIdx.x;
  const int batch = blockIdx.x >> 3;
  const unsigned c7 = (blockIdx.x & 7u) << 7;
  unsigned* stb = st + ((size_t)batch << 16);

  // S1 layout: p = (t<<1) | (j&1) | ((j&14)<<9)  [j0->p0(g0), j1..3 -> p10..12
  // (g13..15)]. Load pairs (j even): dwordx2 at GIDX(p)|c7.
  v2f A[16];
  #pragma unroll
  for (int jp = 0; jp < 8; ++jp) {
    const unsigned p = ((unsigned)t << 1) | ((unsigned)jp << 10);
    const uint2 u = *(const uint2*)(stb + (GIDX(p) | c7));
    A[2*jp]   = UNPK(u.x);
    A[2*jp+1] = UNPK(u.y);
  }

  const unsigned tp1 = GIDX((unsigned)t << 1) | c7;
  gate4<0,13,14,15, 0x8000u,0x8000u>(A, g, 0, tp1);                   // L0 w0
  gate4<0,13,14,15, 0x4000u,0x4000u>(A, g, 1, tp1);                   // L0 w1
  gate4<0,13,14,15, 0x2000u,0x2000u>(A, g, 2, tp1);                   // L0 w2
  gate4<0,13,14,15, META.l1mask[0],  META.l1role[0]> (A, g, 16, tp1); // L1 w0
  gate4<0,13,14,15, META.l1mask[1],  META.l1role[1]> (A, g, 17, tp1); // L1 w1
  gate4<0,13,14,15, META.l1mask[15], META.l1role[15]>(A, g, 31, tp1); // L1 w15

  // E1 -> S2: tsp2 = (t&0x7F)|((t&0x180)<<4), jsp2 = j<<7 (p7..10 = g10..13)
  {
    const unsigned wb = HSH((unsigned)t << 1);
    #pragma unroll
    for (int j = 0; j < 16; ++j)
      L[wb ^ HSH(((unsigned)j & 1u) | (((unsigned)j & 14u) << 9))] = PK(A[j]);
    __syncthreads();
    const unsigned rb = HSH(((unsigned)t & 0x7Fu) | (((unsigned)t & 0x180u) << 4));
    #pragma unroll
    for (int j = 0; j < 16; ++j) A[j] = UNPK(L[rb ^ HSH((unsigned)j << 7)]);
  }

  const unsigned tp2 = GIDX(((unsigned)t & 0x7Fu) | (((unsigned)t & 0x180u) << 4)) | c7;
  gate4<10,11,12,13, META.l1mask[2], META.l1role[2]>(A, g, 18, tp2);
  gate4<10,11,12,13, META.l1mask[3], META.l1role[3]>(A, g, 19, tp2);
  gate4<10,11,12,13, META.l1mask[4], META.l1role[4]>(A, g, 20, tp2);

  // E2 -> S3: tsp3 = (t&7)|((t&0x1F8)<<4), jsp3 = j<<3 (p3..6 = g3..6)
  __syncthreads();
  {
    const unsigned wb = HSH(((unsigned)t & 0x7Fu) | (((unsigned)t & 0x180u) << 4));
    #pragma unroll
    for (int j = 0; j < 16; ++j) L[wb ^ HSH((unsigned)j << 7)] = PK(A[j]);
    __syncthreads();
    const unsigned rb = HSH(((unsigned)t & 7u) | (((unsigned)t & 0x1F8u) << 4));
    #pragma unroll
    for (int j = 0; j < 16; ++j) A[j] = UNPK(L[rb ^ HSH((unsigned)j << 3)]);
  }

  const unsigned tp3 = GIDX(((unsigned)t & 7u) | (((unsigned)t & 0x1F8u) << 4)) | c7;
  gate4<3,4,5,6, META.l1mask[9],  META.l1role[9]> (A, g, 25, tp3);
  gate4<3,4,5,6, META.l1mask[10], META.l1role[10]>(A, g, 26, tp3);
  gate4<3,4,5,6, META.l1mask[11], META.l1role[11]>(A, g, 27, tp3);

  // E3 -> S4: tsp4 = t<<4, jsp4 = j (p0..3 = g0..3)
  __syncthreads();
  {
    const unsigned wb = HSH(((unsigned)t & 7u) | (((unsigned)t & 0x1F8u) << 4));
    #pragma unroll
    for (int j = 0; j < 16; ++j) L[wb ^ HSH((unsigned)j << 3)] = PK(A[j]);
    __syncthreads();
    const unsigned rb = HSH((unsigned)t << 4);
    #pragma unroll
    for (int j = 0; j < 16; ++j) A[j] = UNPK(L[rb ^ HSH((unsigned)j)]);
  }

  const unsigned tp4 = GIDX((unsigned)t << 4) | c7;
  gate4<0,1,2,3, META.l1mask[12], META.l1role[12]>(A, g, 28, tp4);
  gate4<0,1,2,3, META.l1mask[13], META.l1role[13]>(A, g, 29, tp4);
  gate4<0,1,2,3, META.l1mask[14], META.l1role[14]>(A, g, 30, tp4);

  // Store: 16 consecutive dwords at GIDX(t<<4)|c7 (g{3..0} = j) -> 4 dwordx4
  unsigned* outb = stb + (GIDX((unsigned)t << 4) | c7);
  #pragma unroll
  for (int q = 0; q < 4; ++q) {
    uint4 v;
    v.x = PK(A[q*4+0]); v.y = PK(A[q*4+1]); v.z = PK(A[q*4+2]); v.w = PK(A[q*4+3]);
    *(uint4*)(outb + q*4) = v;
  }
}

// ---------------------------------------------------------------------------
// PASS C (unchanged from R2): fixed {15,14,13}=f, reg {6,7,8,9,10}: L1 w5..w8,
// then fused Z-expvals. 256 thr x 32 amps.
// ---------------------------------------------------------------------------
__global__ __launch_bounds__(256, 4) void passC(const unsigned* __restrict__ st,
    const float* __restrict__ g, float* __restrict__ partials) {
  __shared__ float R[4][17];
  const int t = threadIdx.x;
  const int batch = blockIdx.x >> 3;
  const unsigned f = blockIdx.x & 7;
  const unsigned* stb = st + ((size_t)batch << 16);

  const unsigned cbase = (f << 13) | (((unsigned)t & 192u) << 5) | ((unsigned)t & 63u);
  v2f A[32];
  #pragma unroll
  for (int j = 0; j < 32; ++j) A[j] = UNPK(stb[cbase | ((unsigned)j << 6)]);

  gate5<6,7,8,9,10, META.l1mask[5], META.l1role[5]>(A, g, 21, cbase);
  gate5<6,7,8,9,10, META.l1mask[6], META.l1role[6]>(A, g, 22, cbase);
  gate5<6,7,8,9,10, META.l1mask[7], META.l1role[7]>(A, g, 23, cbase);
  gate5<6,7,8,9,10, META.l1mask[8], META.l1role[8]>(A, g, 24, cbase);

  float sv[16], tot = 0.f;
  #pragma unroll
  for (int w = 0; w < 16; ++w) sv[w] = 0.f;
  #pragma unroll
  for (int j = 0; j < 32; ++j) {
    const float pr = A[j].x*A[j].x + A[j].y*A[j].y;
    tot += pr;
    #pragma unroll
    for (int w = 0; w < 16; ++w) {
      const bool neg = (__builtin_popcount(META.fin[w] & ((unsigned)j << 6)) & 1) != 0;
      sv[w] += neg ? -pr : pr;
    }
  }
  #pragma unroll
  for (int w = 0; w < 16; ++w)
    if (__popc(META.fin[w] & cbase) & 1) sv[w] = -sv[w];

  #pragma unroll
  for (int off = 32; off; off >>= 1) {
    tot += __shfl_xor(tot, off, 64);
    #pragma unroll
    for (int w = 0; w < 16; ++w) sv[w] += __shfl_xor(sv[w], off, 64);
  }
  const int wave = t >> 6, lane = t & 63;
  if (lane == 0) {
    #pragma unroll
    for (int w = 0; w < 16; ++w) R[wave][w] = sv[w];
    R[wave][16] = tot;
  }
  __syncthreads();
  if (t < 17) {
    const float s2 = R[0][t] + R[1][t] + R[2][t] + R[3][t];
    partials[(size_t)blockIdx.x * 17 + t] = s2;
  }
}

__global__ __launch_bounds__(64) void head(const float* __restrict__ partials,
    const float* __restrict__ W, const float* __restrict__ bias,
    float* __restrict__ out) {
  const int b = blockIdx.x, tid = threadIdx.x;
  __shared__ float red[17];
  __shared__ float ev[16];
  if (tid < 17) {
    float s = 0.f;
    #pragma unroll
    for (int ch = 0; ch < 8; ++ch) s += partials[(size_t)((b << 3) + ch) * 17 + tid];
    red[tid] = s;
  }
  __syncthreads();
  if (tid < 16) ev[tid] = red[tid] / red[16];
  __syncthreads();
  if (tid < NCLS) {
    float o = bias[tid];
    #pragma unroll
    for (int w = 0; w < 16; ++w) o += ev[w] * W[tid*16 + w];
    out[b*NCLS + tid] = o;
  }
}

extern "C" void kernel_launch(void* const* d_in, const int* in_sizes, int n_in,
                              void* d_out, int out_size, void* d_ws, size_t ws_size,
                              hipStream_t stream) {
  const float* x  = (const float*)d_in[0];   // (256, 65536)
  const float* qp = (const float*)d_in[1];   // (2,16,3)
  const float* W  = (const float*)d_in[2];   // (10,16)
  const float* bv = (const float*)d_in[3];   // (10,)
  float* out = (float*)d_out;                // (256,10) fp32

  unsigned* st     = (unsigned*)d_ws;                                  // 64 MB fp16 state
  float*    gates  = (float*)((char*)d_ws + (size_t)BATCH * 65536 * 4);
  float*    parts  = (float*)((char*)gates + 1024);

  prep_gates<<<dim3(1), dim3(64), 0, stream>>>(qp, gates);
  passA<<<dim3(BATCH*8), dim3(512), 0, stream>>>(x, st, gates);
  passB<<<dim3(BATCH*8), dim3(512), 0, stream>>>(st, gates);
  passC<<<dim3(BATCH*8), dim3(256), 0, stream>>>(st, gates, parts);
  head<<<dim3(BATCH), dim3(64), 0, stream>>>(parts, W, bv, out);
}